// Round 10
// baseline (689.464 us; speedup 1.0000x reference)
//
#include <hip/hip_runtime.h>
#include <hip/hip_fp16.h>

#define NSEQ 8192
#define DIM  512

typedef _Float16 f16;
typedef _Float16 f16x8 __attribute__((ext_vector_type(8)));
typedef _Float16 f16x4 __attribute__((ext_vector_type(4)));
typedef float    f32x4 __attribute__((ext_vector_type(4)));

// S^T fragment layout (16x16 f32, C-native): frag(qt, jt) at
//   ST + ((size_t)qt*512 + jt)*256 ; lane l's 4 values at +l*4
//   value (j = jt*16 + (l>>4)*4 + r, q = qt*16 + (l&15))
// XhTf layout (k-permuted to match B built from two S^T frags):
//   element (d, j): frag = (d>>4)*256 + (j>>5); within: lane = ((j>>2)&3)*16
//   + (d&15); slot e = (j&3) | (((j>>4)&1)<<2); offset frag*512 + lane*8 + e.

// ---------------------------------------------------------------------------
// X (fp32) -> Xh + Xl (f16 hi/lo split), row-major.
// ---------------------------------------------------------------------------
__global__ __launch_bounds__(256) void k_splitx(const float* __restrict__ X,
                                                f16* __restrict__ Xh,
                                                f16* __restrict__ Xl)
{
  const size_t idx = (size_t)blockIdx.x * 256 + threadIdx.x;
  f32x4 v = *(const f32x4*)(X + idx * 4);
  f16x4 h, l;
#pragma unroll
  for (int i = 0; i < 4; ++i) {
    h[i] = (f16)v[i];
    l[i] = (f16)(v[i] - (float)h[i]);
  }
  *(f16x4*)(Xh + idx * 4) = h;
  *(f16x4*)(Xl + idx * 4) = l;
}

// ---------------------------------------------------------------------------
// W (512x512 fp32) -> Wt^T split: Wth/Wtl[c][k] = split(W[k][c]).
// ---------------------------------------------------------------------------
__global__ __launch_bounds__(256) void k_splitwt(const float* __restrict__ W,
                                                 f16* __restrict__ Th,
                                                 f16* __restrict__ Tl)
{
  __shared__ float T[64][65];
  const int tid = threadIdx.x;
  const int k0 = blockIdx.x * 64;
  const int c0 = blockIdx.y * 64;
#pragma unroll
  for (int e = 0; e < 16; ++e) {
    int idx = tid + e * 256;
    T[idx >> 6][idx & 63] = W[(size_t)(k0 + (idx >> 6)) * DIM + c0 + (idx & 63)];
  }
  __syncthreads();
#pragma unroll
  for (int e = 0; e < 16; ++e) {
    int idx = tid + e * 256;
    int cc = idx >> 6, kk = idx & 63;
    float v = T[kk][cc];
    f16 h = (f16)v;
    Th[(size_t)(c0 + cc) * DIM + k0 + kk] = h;
    Tl[(size_t)(c0 + cc) * DIM + k0 + kk] = (f16)(v - (float)h);
  }
}

// ---------------------------------------------------------------------------
// X -> XhTf: k-permuted frag-tiled V^T (rows = d, k-cols = j).
// ---------------------------------------------------------------------------
__global__ __launch_bounds__(256) void k_xt2(const float* __restrict__ X,
                                             f16* __restrict__ XhTf)
{
  __shared__ float T[64][65];
  const int tid = threadIdx.x;
  const int j0 = blockIdx.x * 64;
  const int d0 = blockIdx.y * 64;
#pragma unroll
  for (int e = 0; e < 16; ++e) {
    int idx = tid + e * 256;
    T[idx >> 6][idx & 63] = X[(size_t)(j0 + (idx >> 6)) * DIM + d0 + (idx & 63)];
  }
  __syncthreads();
#pragma unroll
  for (int e = 0; e < 16; ++e) {
    int idx = tid + e * 256;
    int dd = idx >> 6, jj = idx & 63;
    int d = d0 + dd, j = j0 + jj;
    int lane = ((j >> 2) & 3) * 16 + (d & 15);
    int slot = (j & 3) | (((j >> 4) & 1) << 2);
    size_t off = ((size_t)(d >> 4) * 256 + (j >> 5)) * 512 + lane * 8 + slot;
    XhTf[off] = (f16)T[jj][dd];
  }
}

// ---------------------------------------------------------------------------
// Projection via split-f16 MFMA: C = X W  (M=8192, N=512, K=512).
// 128x128 tile, 4 waves, BK=32, 3-term split, XOR-swizzled LDS.
// Epilogue: c *= scale, split into Oh/Ol row-major (pitch DIM).
// ---------------------------------------------------------------------------
__global__ __launch_bounds__(256) void k_proj(
    const f16* __restrict__ Xh, const f16* __restrict__ Xl,
    const f16* __restrict__ Wth, const f16* __restrict__ Wtl,
    f16* __restrict__ Oh, f16* __restrict__ Ol, float scale)
{
  __shared__ char sm[4 * 8192];
  const int tid  = threadIdx.x;
  const int lane = tid & 63;
  const int w    = tid >> 6;
  const int wm   = (w >> 1) * 64;
  const int wn   = (w & 1) * 64;
  const int row0g = blockIdx.x * 128;
  const int col0g = blockIdx.y * 128;

  const int r1 = tid >> 2;
  const int o1 = (tid & 3) * 8;
  const int sw1 = (r1 * 64 + (tid & 3) * 16) ^ ((r1 & 7) << 4);
  const int sw2 = ((r1 + 64) * 64 + (tid & 3) * 16) ^ (((r1 + 64) & 7) << 4);
  const f16* pAh = Xh  + (size_t)(row0g + r1) * DIM + o1;
  const f16* pAl = Xl  + (size_t)(row0g + r1) * DIM + o1;
  const f16* pBh = Wth + (size_t)(col0g + r1) * DIM + o1;
  const f16* pBl = Wtl + (size_t)(col0g + r1) * DIM + o1;
  const int R64 = 64 * DIM;

  const int frow = lane & 15;
  const int fkb  = (lane >> 4) * 16;

  f32x4 acc[4][4] = {};

  for (int step = 0; step < 16; ++step) {
    const int d0 = step * 32;
    uint4 v0 = *(const uint4*)(pAh + d0);
    uint4 v1 = *(const uint4*)(pAh + R64 + d0);
    uint4 v2 = *(const uint4*)(pAl + d0);
    uint4 v3 = *(const uint4*)(pAl + R64 + d0);
    uint4 v4 = *(const uint4*)(pBh + d0);
    uint4 v5 = *(const uint4*)(pBh + R64 + d0);
    uint4 v6 = *(const uint4*)(pBl + d0);
    uint4 v7 = *(const uint4*)(pBl + R64 + d0);
    __syncthreads();
    *(uint4*)(sm +     0 + sw1) = v0;
    *(uint4*)(sm +     0 + sw2) = v1;
    *(uint4*)(sm +  8192 + sw1) = v2;
    *(uint4*)(sm +  8192 + sw2) = v3;
    *(uint4*)(sm + 16384 + sw1) = v4;
    *(uint4*)(sm + 16384 + sw2) = v5;
    *(uint4*)(sm + 24576 + sw1) = v6;
    *(uint4*)(sm + 24576 + sw2) = v7;
    __syncthreads();
    f16x8 aH[4], aL[4], bH[4], bL[4];
#pragma unroll
    for (int m = 0; m < 4; ++m) {
      int ra = wm + m * 16 + frow;
      int rb = wn + m * 16 + frow;
      int sa = (ra * 64 + fkb) ^ ((ra & 7) << 4);
      int sb = (rb * 64 + fkb) ^ ((rb & 7) << 4);
      aH[m] = *(const f16x8*)(sm +     0 + sa);
      aL[m] = *(const f16x8*)(sm +  8192 + sa);
      bH[m] = *(const f16x8*)(sm + 16384 + sb);
      bL[m] = *(const f16x8*)(sm + 24576 + sb);
    }
#pragma unroll
    for (int m = 0; m < 4; ++m)
#pragma unroll
      for (int n = 0; n < 4; ++n) {
        acc[m][n] = __builtin_amdgcn_mfma_f32_16x16x32_f16(aH[m], bH[n], acc[m][n], 0, 0, 0);
        acc[m][n] = __builtin_amdgcn_mfma_f32_16x16x32_f16(aH[m], bL[n], acc[m][n], 0, 0, 0);
        acc[m][n] = __builtin_amdgcn_mfma_f32_16x16x32_f16(aL[m], bH[n], acc[m][n], 0, 0, 0);
      }
  }

  const int row0 = row0g + wm;
  const int col0 = col0g + wn;
#pragma unroll
  for (int m = 0; m < 4; ++m)
#pragma unroll
    for (int n = 0; n < 4; ++n) {
      int row = row0 + m * 16 + (lane >> 4) * 4;
      int col = col0 + n * 16 + frow;
#pragma unroll
      for (int r = 0; r < 4; ++r) {
        float c = acc[m][n][r] * scale;
        f16 h = (f16)c;
        Oh[(size_t)(row + r) * DIM + col] = h;
        Ol[(size_t)(row + r) * DIM + col] = (f16)(c - (float)h);
      }
    }
}

// ---------------------------------------------------------------------------
// S^T = K Q^T via split-f16 MFMA (3 mfma per pair). A = K rows (j), B = Q
// rows (q). 128x128 tile, 4 waves, BK=32, XOR-swizzled LDS. Epilogue writes
// C-native 16x16 f32 frags, coalesced (lane l -> frag + l*16B).
// ---------------------------------------------------------------------------
__global__ __launch_bounds__(256) void k_qkt_t(
    const f16* __restrict__ Kh, const f16* __restrict__ Kl,
    const f16* __restrict__ Qh, const f16* __restrict__ Ql,
    float* __restrict__ ST, int q0)
{
  __shared__ char sm[4 * 8192];
  const int tid  = threadIdx.x;
  const int lane = tid & 63;
  const int w    = tid >> 6;
  const int wm   = (w >> 1) * 64;          // j offset in tile
  const int wn   = (w & 1) * 64;           // q offset in tile
  const int jrow0 = blockIdx.x * 128;
  const int qrow0 = q0 + blockIdx.y * 128;

  const int r1 = tid >> 2;
  const int o1 = (tid & 3) * 8;
  const int sw1 = (r1 * 64 + (tid & 3) * 16) ^ ((r1 & 7) << 4);
  const int sw2 = ((r1 + 64) * 64 + (tid & 3) * 16) ^ (((r1 + 64) & 7) << 4);
  const f16* pAh = Kh + (size_t)(jrow0 + r1) * DIM + o1;
  const f16* pAl = Kl + (size_t)(jrow0 + r1) * DIM + o1;
  const f16* pBh = Qh + (size_t)(qrow0 + r1) * DIM + o1;
  const f16* pBl = Ql + (size_t)(qrow0 + r1) * DIM + o1;
  const int R64 = 64 * DIM;

  const int frow = lane & 15;
  const int fkb  = (lane >> 4) * 16;

  f32x4 acc[4][4] = {};

  for (int step = 0; step < 16; ++step) {
    const int d0 = step * 32;
    uint4 v0 = *(const uint4*)(pAh + d0);
    uint4 v1 = *(const uint4*)(pAh + R64 + d0);
    uint4 v2 = *(const uint4*)(pAl + d0);
    uint4 v3 = *(const uint4*)(pAl + R64 + d0);
    uint4 v4 = *(const uint4*)(pBh + d0);
    uint4 v5 = *(const uint4*)(pBh + R64 + d0);
    uint4 v6 = *(const uint4*)(pBl + d0);
    uint4 v7 = *(const uint4*)(pBl + R64 + d0);
    __syncthreads();
    *(uint4*)(sm +     0 + sw1) = v0;
    *(uint4*)(sm +     0 + sw2) = v1;
    *(uint4*)(sm +  8192 + sw1) = v2;
    *(uint4*)(sm +  8192 + sw2) = v3;
    *(uint4*)(sm + 16384 + sw1) = v4;
    *(uint4*)(sm + 16384 + sw2) = v5;
    *(uint4*)(sm + 24576 + sw1) = v6;
    *(uint4*)(sm + 24576 + sw2) = v7;
    __syncthreads();
    f16x8 aH[4], aL[4], bH[4], bL[4];
#pragma unroll
    for (int m = 0; m < 4; ++m) {
      int ra = wm + m * 16 + frow;
      int rb = wn + m * 16 + frow;
      int sa = (ra * 64 + fkb) ^ ((ra & 7) << 4);
      int sb = (rb * 64 + fkb) ^ ((rb & 7) << 4);
      aH[m] = *(const f16x8*)(sm +     0 + sa);
      aL[m] = *(const f16x8*)(sm +  8192 + sa);
      bH[m] = *(const f16x8*)(sm + 16384 + sb);
      bL[m] = *(const f16x8*)(sm + 24576 + sb);
    }
#pragma unroll
    for (int m = 0; m < 4; ++m)
#pragma unroll
      for (int n = 0; n < 4; ++n) {
        acc[m][n] = __builtin_amdgcn_mfma_f32_16x16x32_f16(aH[m], bH[n], acc[m][n], 0, 0, 0);
        acc[m][n] = __builtin_amdgcn_mfma_f32_16x16x32_f16(aH[m], bL[n], acc[m][n], 0, 0, 0);
        acc[m][n] = __builtin_amdgcn_mfma_f32_16x16x32_f16(aL[m], bH[n], acc[m][n], 0, 0, 0);
      }
  }

  // C rows = j (A), cols = q (B). Write native frags: frag(qt, jt) + lane*4.
  const int jt0 = (blockIdx.x * 128 + wm) >> 4;
  const int qt0 = (blockIdx.y * 128 + wn) >> 4;   // chunk-local
#pragma unroll
  for (int m = 0; m < 4; ++m)
#pragma unroll
    for (int n = 0; n < 4; ++n) {
      float* dst = ST + ((size_t)(qt0 + n) * 512 + (jt0 + m)) * 256 + lane * 4;
      *(f32x4*)dst = acc[m][n];
    }
}

// ---------------------------------------------------------------------------
// Row max over S^T frags. One block per 16-q group; waves split jt.
// ---------------------------------------------------------------------------
__global__ __launch_bounds__(256) void k_smax(
    const float* __restrict__ ST, float* __restrict__ mrow, int q0)
{
  __shared__ float red[4][16];
  const int tid  = threadIdx.x;
  const int lane = tid & 63;
  const int w    = tid >> 6;
  const int qt   = blockIdx.x;
  const float* base = ST + ((size_t)qt * 512 + w * 128) * 256 + lane * 4;
  float mx = -3.0e38f;
#pragma unroll 4
  for (int i = 0; i < 128; ++i) {
    f32x4 v = *(const f32x4*)(base + (size_t)i * 256);
    mx = fmaxf(fmaxf(mx, fmaxf(v[0], v[1])), fmaxf(v[2], v[3]));
  }
  mx = fmaxf(mx, __shfl_xor(mx, 16));
  mx = fmaxf(mx, __shfl_xor(mx, 32));
  if (lane < 16) red[w][lane] = mx;
  __syncthreads();
  if (tid < 16)
    mrow[q0 + qt * 16 + tid] =
        fmaxf(fmaxf(red[0][tid], red[1][tid]), fmaxf(red[2][tid], red[3][tid]));
}

// ---------------------------------------------------------------------------
// Fused exp + PV: Opart^T = XhTf * exp(S^T - m)^T, l = row sums.
// Block = 4 waves = 16 q x 512 d (waves split d). B-frag = two consecutive
// 1KB S^T frag loads + 8 exp + f16 pack (no LDS, no barriers, no shuffles —
// the induced k-permutation is baked into XhTf). xcd-pinned z decode.
// ---------------------------------------------------------------------------
__global__ __launch_bounds__(256, 4) void k_pvx(
    const f16* __restrict__ XhTf, const float* __restrict__ ST,
    const float* __restrict__ mrow, float* __restrict__ obase, size_t zstride,
    float* __restrict__ lpart, int q0, int jrange, int Z)
{
  const int tid  = threadIdx.x;
  const int lane = tid & 63;
  const int w    = tid >> 6;

  const int bid = blockIdx.x;
  const int xcd = bid & 7;
  const int pz  = 8 / Z;                  // Z in {1,2,4}
  const int z   = xcd / pz;
  const int qt  = (bid >> 3) * pz + (xcd % pz);   // chunk-local 16-q group
  const int qg0 = q0 + qt * 16;

  const float mv = mrow[qg0 + (lane & 15)];

  // A: fragcol walk over this z's j-slice; 8 d-groups per wave.
  const f16* pa = XhTf + ((size_t)(w * 8) * 256 + (z * jrange >> 5)) * 512 + lane * 8;
  // B: S^T frags for q-group qt, jt from this z's slice.
  const float* pb = ST + ((size_t)qt * 512 + (z * jrange >> 4)) * 256 + lane * 4;

  f32x4 acc[8] = {};
  float lsum = 0.f;
  const int nsteps = jrange / 32;

#pragma unroll 2
  for (int s = 0; s < nsteps; ++s) {
    f32x4 s0 = *(const f32x4*)(pb + (size_t)(2 * s) * 256);
    f32x4 s1 = *(const f32x4*)(pb + (size_t)(2 * s + 1) * 256);
    f16x8 b;
#pragma unroll
    for (int i = 0; i < 4; ++i) {
      float p = __expf(s0[i] - mv);
      lsum += p;
      b[i] = (f16)p;
    }
#pragma unroll
    for (int i = 0; i < 4; ++i) {
      float p = __expf(s1[i] - mv);
      lsum += p;
      b[4 + i] = (f16)p;
    }
#pragma unroll
    for (int m2 = 0; m2 < 8; ++m2) {
      f16x8 a = *(const f16x8*)(pa + ((size_t)m2 * 256 + s) * 512);
      acc[m2] = __builtin_amdgcn_mfma_f32_16x16x32_f16(a, b, acc[m2], 0, 0, 0);
    }
  }

  // l: identical across waves; wave 0 stores (lanes sharing l&15 combined).
  lsum += __shfl_xor(lsum, 16);
  lsum += __shfl_xor(lsum, 32);
  if (w == 0 && lane < 16)
    lpart[(size_t)z * NSEQ + qg0 + lane] = lsum;

  // C: row = d = w*128 + m2*16 + (lane>>4)*4 + r ; col = q = qg0 + (lane&15)
  const int qg = qg0 + (lane & 15);
  float* op = obase + (size_t)z * zstride + (size_t)qg * DIM;
#pragma unroll
  for (int m2 = 0; m2 < 8; ++m2)
    *(f32x4*)(op + w * 128 + m2 * 16 + (lane >> 4) * 4) = acc[m2];
}

// ---------------------------------------------------------------------------
// Out[q][d] = (sum_z Opart[z][q][d]) / (sum_z lpart[z][q]).
// Works in place when obase==Out (Z==1, zstride==0).
// ---------------------------------------------------------------------------
__global__ __launch_bounds__(256) void k_reduce2(
    const float* __restrict__ obase, size_t zstride, int Z,
    const float* __restrict__ lpart, float* __restrict__ Out)
{
  const int idx = blockIdx.x * 256 + threadIdx.x;
  const int q = idx >> 7;
  const int d4 = idx & 127;
  const float* p = obase + (size_t)q * DIM + (size_t)d4 * 4;
  f32x4 s = *(const f32x4*)p;
  float l = lpart[q];
  for (int zz = 1; zz < Z; ++zz) {
    s += *(const f32x4*)(p + (size_t)zz * zstride);
    l += lpart[(size_t)zz * NSEQ + q];
  }
  s *= (1.0f / l);
  *(f32x4*)(Out + (size_t)q * DIM + d4 * 4) = s;
}

// ---------------------------------------------------------------------------
extern "C" void kernel_launch(void* const* d_in, const int* in_sizes, int n_in,
                              void* d_out, int out_size, void* d_ws, size_t ws_size,
                              hipStream_t stream) {
  const float* Wq = (const float*)d_in[0];
  const float* Wk = (const float*)d_in[1];
  const float* X  = (const float*)d_in[2];
  float* Out = (float*)d_out;

  char* w = (char*)d_ws;
  const size_t SPLIT = (size_t)NSEQ * DIM * 2;           // 8 MB
  const size_t XFB   = (size_t)NSEQ * DIM * 2;           // 8 MB frag XhTf
  const size_t WTB   = (size_t)DIM * DIM * 2;            // 512 KB
  f16* Qh   = (f16*)(w);
  f16* Ql   = (f16*)(w + SPLIT);
  f16* Kh   = (f16*)(w + 2 * SPLIT);
  f16* Kl   = (f16*)(w + 3 * SPLIT);
  f16* XhTf = (f16*)(w + 4 * SPLIT);
  f16* Xh   = (f16*)(w + 4 * SPLIT + XFB);
  f16* Xl   = (f16*)(w + 5 * SPLIT + XFB);
  f16* Wth  = (f16*)(w + 6 * SPLIT + XFB);
  f16* Wtl  = (f16*)(w + 6 * SPLIT + XFB + WTB);
  float* mrow  = (float*)(w + 6 * SPLIT + XFB + 2 * WTB);              // 32 KB
  float* lpart = (float*)(w + 6 * SPLIT + XFB + 2 * WTB + 32768);      // 128 KB
  const size_t used_base = 6 * SPLIT + XFB + 2 * WTB + 163840;
  char* rest = w + used_base;
  const size_t OPART1 = (size_t)NSEQ * DIM * 4;          // 16 MB per partial
  const size_t avail = (ws_size > used_base) ? ws_size - used_base : 0;

  // pick (CQ, Z): ST chunk = CQ*32KB; partials = Z*16MB (Z>1).
  int CQ = 4096, Z = 4;
  auto need = [&](int cq, int zz) -> size_t {
    return (size_t)cq * NSEQ * 4 + (zz > 1 ? (size_t)zz * OPART1 : 0);
  };
  if (need(CQ, Z) > avail) { CQ = 2048; }
  if (need(CQ, Z) > avail) { Z = 2; }
  if (need(CQ, Z) > avail) { CQ = 1024; }
  if (need(CQ, Z) > avail) { Z = 1; }
  if (need(CQ, Z) > avail) { CQ = 512; }
  if (need(CQ, Z) > avail) { CQ = 256; }

  float* ST = (float*)rest;
  float* obase; size_t zstride;
  if (Z > 1) { obase = (float*)(rest + (size_t)CQ * NSEQ * 4); zstride = (size_t)NSEQ * DIM; }
  else       { obase = Out; zstride = 0; }

  const float SCALE = 0.044194173824159216f;  // 1/sqrt(512)
  k_splitx<<<NSEQ * DIM / (256 * 4), 256, 0, stream>>>(X, Xh, Xl);
  k_xt2<<<dim3(NSEQ / 64, DIM / 64), 256, 0, stream>>>(X, XhTf);
  k_splitwt<<<dim3(8, 8), 256, 0, stream>>>(Wq, Wth, Wtl);
  k_proj<<<dim3(NSEQ / 128, DIM / 128), 256, 0, stream>>>(Xh, Xl, Wth, Wtl, Qh, Ql, SCALE);
  k_splitwt<<<dim3(8, 8), 256, 0, stream>>>(Wk, Wth, Wtl);
  k_proj<<<dim3(NSEQ / 128, DIM / 128), 256, 0, stream>>>(Xh, Xl, Wth, Wtl, Kh, Kl, 1.0f);

  for (int q0 = 0; q0 < NSEQ; q0 += CQ) {
    k_qkt_t<<<dim3(NSEQ / 128, CQ / 128), 256, 0, stream>>>(Kh, Kl, Qh, Ql, ST, q0);
    k_smax<<<dim3(CQ / 16), 256, 0, stream>>>(ST, mrow, q0);
    k_pvx<<<dim3((CQ / 16) * Z), 256, 0, stream>>>(XhTf, ST, mrow, obase, zstride,
                                                   lpart, q0, NSEQ / Z, Z);
  }
  k_reduce2<<<NSEQ * (DIM / 4) / 256, 256, 0, stream>>>(obase, zstride, Z, lpart, Out);
}

// Round 11
// 604.236 us; speedup vs baseline: 1.1411x; 1.1411x over previous
//
#include <hip/hip_runtime.h>
#include <hip/hip_fp16.h>

#define NSEQ 8192
#define DIM  512

typedef _Float16 f16;
typedef _Float16 f16x8 __attribute__((ext_vector_type(8)));
typedef _Float16 f16x4 __attribute__((ext_vector_type(4)));
typedef float    f32x4 __attribute__((ext_vector_type(4)));

// S^T fragment layout (16x16 f32, C-native): frag(qt, jt) at
//   ST + ((size_t)qt*512 + jt)*256 ; lane l's 4 values at +l*4
//   value (j = jt*16 + (l>>4)*4 + r, q = qt*16 + (l&15))
// XhTf layout (k-permuted to match B built from two S^T frags):
//   element (d, j): frag = (d>>4)*256 + (j>>5); within: lane = ((j>>2)&3)*16
//   + (d&15); slot e = (j&3) | (((j>>4)&1)<<2); offset frag*512 + lane*8 + e.

// ---------------------------------------------------------------------------
// X (fp32) -> Xh + Xl (f16 hi/lo split), row-major.
// ---------------------------------------------------------------------------
__global__ __launch_bounds__(256) void k_splitx(const float* __restrict__ X,
                                                f16* __restrict__ Xh,
                                                f16* __restrict__ Xl)
{
  const size_t idx = (size_t)blockIdx.x * 256 + threadIdx.x;
  f32x4 v = *(const f32x4*)(X + idx * 4);
  f16x4 h, l;
#pragma unroll
  for (int i = 0; i < 4; ++i) {
    h[i] = (f16)v[i];
    l[i] = (f16)(v[i] - (float)h[i]);
  }
  *(f16x4*)(Xh + idx * 4) = h;
  *(f16x4*)(Xl + idx * 4) = l;
}

// ---------------------------------------------------------------------------
// W (512x512 fp32) -> Wt^T split: Wth/Wtl[c][k] = split(W[k][c]).
// ---------------------------------------------------------------------------
__global__ __launch_bounds__(256) void k_splitwt(const float* __restrict__ W,
                                                 f16* __restrict__ Th,
                                                 f16* __restrict__ Tl)
{
  __shared__ float T[64][65];
  const int tid = threadIdx.x;
  const int k0 = blockIdx.x * 64;
  const int c0 = blockIdx.y * 64;
#pragma unroll
  for (int e = 0; e < 16; ++e) {
    int idx = tid + e * 256;
    T[idx >> 6][idx & 63] = W[(size_t)(k0 + (idx >> 6)) * DIM + c0 + (idx & 63)];
  }
  __syncthreads();
#pragma unroll
  for (int e = 0; e < 16; ++e) {
    int idx = tid + e * 256;
    int cc = idx >> 6, kk = idx & 63;
    float v = T[kk][cc];
    f16 h = (f16)v;
    Th[(size_t)(c0 + cc) * DIM + k0 + kk] = h;
    Tl[(size_t)(c0 + cc) * DIM + k0 + kk] = (f16)(v - (float)h);
  }
}

// ---------------------------------------------------------------------------
// X -> XhTf: k-permuted frag-tiled V^T (rows = d, k-cols = j).
// ---------------------------------------------------------------------------
__global__ __launch_bounds__(256) void k_xt2(const float* __restrict__ X,
                                             f16* __restrict__ XhTf)
{
  __shared__ float T[64][65];
  const int tid = threadIdx.x;
  const int j0 = blockIdx.x * 64;
  const int d0 = blockIdx.y * 64;
#pragma unroll
  for (int e = 0; e < 16; ++e) {
    int idx = tid + e * 256;
    T[idx >> 6][idx & 63] = X[(size_t)(j0 + (idx >> 6)) * DIM + d0 + (idx & 63)];
  }
  __syncthreads();
#pragma unroll
  for (int e = 0; e < 16; ++e) {
    int idx = tid + e * 256;
    int dd = idx >> 6, jj = idx & 63;
    int d = d0 + dd, j = j0 + jj;
    int lane = ((j >> 2) & 3) * 16 + (d & 15);
    int slot = (j & 3) | (((j >> 4) & 1) << 2);
    size_t off = ((size_t)(d >> 4) * 256 + (j >> 5)) * 512 + lane * 8 + slot;
    XhTf[off] = (f16)T[jj][dd];
  }
}

// ---------------------------------------------------------------------------
// Projection via split-f16 MFMA: C = X W  (M=8192, N=512, K=512).
// 128x128 tile, 4 waves, BK=32, 3-term split, XOR-swizzled LDS.
// ---------------------------------------------------------------------------
__global__ __launch_bounds__(256) void k_proj(
    const f16* __restrict__ Xh, const f16* __restrict__ Xl,
    const f16* __restrict__ Wth, const f16* __restrict__ Wtl,
    f16* __restrict__ Oh, f16* __restrict__ Ol, float scale)
{
  __shared__ char sm[4 * 8192];
  const int tid  = threadIdx.x;
  const int lane = tid & 63;
  const int w    = tid >> 6;
  const int wm   = (w >> 1) * 64;
  const int wn   = (w & 1) * 64;
  const int row0g = blockIdx.x * 128;
  const int col0g = blockIdx.y * 128;

  const int r1 = tid >> 2;
  const int o1 = (tid & 3) * 8;
  const int sw1 = (r1 * 64 + (tid & 3) * 16) ^ ((r1 & 7) << 4);
  const int sw2 = ((r1 + 64) * 64 + (tid & 3) * 16) ^ (((r1 + 64) & 7) << 4);
  const f16* pAh = Xh  + (size_t)(row0g + r1) * DIM + o1;
  const f16* pAl = Xl  + (size_t)(row0g + r1) * DIM + o1;
  const f16* pBh = Wth + (size_t)(col0g + r1) * DIM + o1;
  const f16* pBl = Wtl + (size_t)(col0g + r1) * DIM + o1;
  const int R64 = 64 * DIM;

  const int frow = lane & 15;
  const int fkb  = (lane >> 4) * 16;

  f32x4 acc[4][4] = {};

  for (int step = 0; step < 16; ++step) {
    const int d0 = step * 32;
    uint4 v0 = *(const uint4*)(pAh + d0);
    uint4 v1 = *(const uint4*)(pAh + R64 + d0);
    uint4 v2 = *(const uint4*)(pAl + d0);
    uint4 v3 = *(const uint4*)(pAl + R64 + d0);
    uint4 v4 = *(const uint4*)(pBh + d0);
    uint4 v5 = *(const uint4*)(pBh + R64 + d0);
    uint4 v6 = *(const uint4*)(pBl + d0);
    uint4 v7 = *(const uint4*)(pBl + R64 + d0);
    __syncthreads();
    *(uint4*)(sm +     0 + sw1) = v0;
    *(uint4*)(sm +     0 + sw2) = v1;
    *(uint4*)(sm +  8192 + sw1) = v2;
    *(uint4*)(sm +  8192 + sw2) = v3;
    *(uint4*)(sm + 16384 + sw1) = v4;
    *(uint4*)(sm + 16384 + sw2) = v5;
    *(uint4*)(sm + 24576 + sw1) = v6;
    *(uint4*)(sm + 24576 + sw2) = v7;
    __syncthreads();
    f16x8 aH[4], aL[4], bH[4], bL[4];
#pragma unroll
    for (int m = 0; m < 4; ++m) {
      int ra = wm + m * 16 + frow;
      int rb = wn + m * 16 + frow;
      int sa = (ra * 64 + fkb) ^ ((ra & 7) << 4);
      int sb = (rb * 64 + fkb) ^ ((rb & 7) << 4);
      aH[m] = *(const f16x8*)(sm +     0 + sa);
      aL[m] = *(const f16x8*)(sm +  8192 + sa);
      bH[m] = *(const f16x8*)(sm + 16384 + sb);
      bL[m] = *(const f16x8*)(sm + 24576 + sb);
    }
#pragma unroll
    for (int m = 0; m < 4; ++m)
#pragma unroll
      for (int n = 0; n < 4; ++n) {
        acc[m][n] = __builtin_amdgcn_mfma_f32_16x16x32_f16(aH[m], bH[n], acc[m][n], 0, 0, 0);
        acc[m][n] = __builtin_amdgcn_mfma_f32_16x16x32_f16(aH[m], bL[n], acc[m][n], 0, 0, 0);
        acc[m][n] = __builtin_amdgcn_mfma_f32_16x16x32_f16(aL[m], bH[n], acc[m][n], 0, 0, 0);
      }
  }

  const int row0 = row0g + wm;
  const int col0 = col0g + wn;
#pragma unroll
  for (int m = 0; m < 4; ++m)
#pragma unroll
    for (int n = 0; n < 4; ++n) {
      int row = row0 + m * 16 + (lane >> 4) * 4;
      int col = col0 + n * 16 + frow;
#pragma unroll
      for (int r = 0; r < 4; ++r) {
        float c = acc[m][n][r] * scale;
        f16 h = (f16)c;
        Oh[(size_t)(row + r) * DIM + col] = h;
        Ol[(size_t)(row + r) * DIM + col] = (f16)(c - (float)h);
      }
    }
}

// ---------------------------------------------------------------------------
// S^T = K Q^T via split-f16 MFMA. Epilogue writes C-native 16x16 f32 frags,
// coalesced (lane l -> frag + l*16B).
// ---------------------------------------------------------------------------
__global__ __launch_bounds__(256) void k_qkt_t(
    const f16* __restrict__ Kh, const f16* __restrict__ Kl,
    const f16* __restrict__ Qh, const f16* __restrict__ Ql,
    float* __restrict__ ST, int q0)
{
  __shared__ char sm[4 * 8192];
  const int tid  = threadIdx.x;
  const int lane = tid & 63;
  const int w    = tid >> 6;
  const int wm   = (w >> 1) * 64;          // j offset in tile
  const int wn   = (w & 1) * 64;           // q offset in tile
  const int jrow0 = blockIdx.x * 128;
  const int qrow0 = q0 + blockIdx.y * 128;

  const int r1 = tid >> 2;
  const int o1 = (tid & 3) * 8;
  const int sw1 = (r1 * 64 + (tid & 3) * 16) ^ ((r1 & 7) << 4);
  const int sw2 = ((r1 + 64) * 64 + (tid & 3) * 16) ^ (((r1 + 64) & 7) << 4);
  const f16* pAh = Kh + (size_t)(jrow0 + r1) * DIM + o1;
  const f16* pAl = Kl + (size_t)(jrow0 + r1) * DIM + o1;
  const f16* pBh = Qh + (size_t)(qrow0 + r1) * DIM + o1;
  const f16* pBl = Ql + (size_t)(qrow0 + r1) * DIM + o1;
  const int R64 = 64 * DIM;

  const int frow = lane & 15;
  const int fkb  = (lane >> 4) * 16;

  f32x4 acc[4][4] = {};

  for (int step = 0; step < 16; ++step) {
    const int d0 = step * 32;
    uint4 v0 = *(const uint4*)(pAh + d0);
    uint4 v1 = *(const uint4*)(pAh + R64 + d0);
    uint4 v2 = *(const uint4*)(pAl + d0);
    uint4 v3 = *(const uint4*)(pAl + R64 + d0);
    uint4 v4 = *(const uint4*)(pBh + d0);
    uint4 v5 = *(const uint4*)(pBh + R64 + d0);
    uint4 v6 = *(const uint4*)(pBl + d0);
    uint4 v7 = *(const uint4*)(pBl + R64 + d0);
    __syncthreads();
    *(uint4*)(sm +     0 + sw1) = v0;
    *(uint4*)(sm +     0 + sw2) = v1;
    *(uint4*)(sm +  8192 + sw1) = v2;
    *(uint4*)(sm +  8192 + sw2) = v3;
    *(uint4*)(sm + 16384 + sw1) = v4;
    *(uint4*)(sm + 16384 + sw2) = v5;
    *(uint4*)(sm + 24576 + sw1) = v6;
    *(uint4*)(sm + 24576 + sw2) = v7;
    __syncthreads();
    f16x8 aH[4], aL[4], bH[4], bL[4];
#pragma unroll
    for (int m = 0; m < 4; ++m) {
      int ra = wm + m * 16 + frow;
      int rb = wn + m * 16 + frow;
      int sa = (ra * 64 + fkb) ^ ((ra & 7) << 4);
      int sb = (rb * 64 + fkb) ^ ((rb & 7) << 4);
      aH[m] = *(const f16x8*)(sm +     0 + sa);
      aL[m] = *(const f16x8*)(sm +  8192 + sa);
      bH[m] = *(const f16x8*)(sm + 16384 + sb);
      bL[m] = *(const f16x8*)(sm + 24576 + sb);
    }
#pragma unroll
    for (int m = 0; m < 4; ++m)
#pragma unroll
      for (int n = 0; n < 4; ++n) {
        acc[m][n] = __builtin_amdgcn_mfma_f32_16x16x32_f16(aH[m], bH[n], acc[m][n], 0, 0, 0);
        acc[m][n] = __builtin_amdgcn_mfma_f32_16x16x32_f16(aH[m], bL[n], acc[m][n], 0, 0, 0);
        acc[m][n] = __builtin_amdgcn_mfma_f32_16x16x32_f16(aL[m], bH[n], acc[m][n], 0, 0, 0);
      }
  }

  const int jt0 = (blockIdx.x * 128 + wm) >> 4;
  const int qt0 = (blockIdx.y * 128 + wn) >> 4;   // chunk-local
#pragma unroll
  for (int m = 0; m < 4; ++m)
#pragma unroll
    for (int n = 0; n < 4; ++n) {
      float* dst = ST + ((size_t)(qt0 + n) * 512 + (jt0 + m)) * 256 + lane * 4;
      *(f32x4*)dst = acc[m][n];
    }
}

// ---------------------------------------------------------------------------
// Row max over S^T frags. One block per 16-q group; waves split jt.
// ---------------------------------------------------------------------------
__global__ __launch_bounds__(256) void k_smax(
    const float* __restrict__ ST, float* __restrict__ mrow, int q0)
{
  __shared__ float red[4][16];
  const int tid  = threadIdx.x;
  const int lane = tid & 63;
  const int w    = tid >> 6;
  const int qt   = blockIdx.x;
  const float* base = ST + ((size_t)qt * 512 + w * 128) * 256 + lane * 4;
  float mx = -3.0e38f;
#pragma unroll 4
  for (int i = 0; i < 128; ++i) {
    f32x4 v = *(const f32x4*)(base + (size_t)i * 256);
    mx = fmaxf(fmaxf(mx, fmaxf(v[0], v[1])), fmaxf(v[2], v[3]));
  }
  mx = fmaxf(mx, __shfl_xor(mx, 16));
  mx = fmaxf(mx, __shfl_xor(mx, 32));
  if (lane < 16) red[w][lane] = mx;
  __syncthreads();
  if (tid < 16)
    mrow[q0 + qt * 16 + tid] =
        fmaxf(fmaxf(red[0][tid], red[1][tid]), fmaxf(red[2][tid], red[3][tid]));
}

// ---------------------------------------------------------------------------
// Fused exp + PV, ILP edition: Opart^T = XhTf * exp(S^T - m)^T, l = row sums.
// Block = 4 waves = 32 q x 512 d. Per step: 4 ST frag loads + 16 exp build
// two B ops; 8 A loads feed 16 MFMA. Explicit double-buffered registers
// (a0/a1, current/next ST) so all of step s+1's loads are in flight during
// step s's MFMAs. xcd-pinned z decode. No LDS, no barriers.
// ---------------------------------------------------------------------------
__global__ __launch_bounds__(256, 2) void k_pvx2(
    const f16* __restrict__ XhTf, const float* __restrict__ ST,
    const float* __restrict__ mrow, float* __restrict__ obase, size_t zstride,
    float* __restrict__ lpart, int q0, int jrange, int Z)
{
  const int tid  = threadIdx.x;
  const int lane = tid & 63;
  const int w    = tid >> 6;

  const int bid = blockIdx.x;
  const int xcd = bid & 7;
  const int pz  = 8 / Z;                  // Z in {1,2,4}
  const int z   = xcd / pz;
  const int qt32 = (bid >> 3) * pz + (xcd % pz);   // chunk-local 32-q group
  const int qg0 = q0 + qt32 * 32;

  const float mv0 = mrow[qg0 + (lane & 15)];
  const float mv1 = mrow[qg0 + 16 + (lane & 15)];

  // A: fragcol walk over this z's j-slice; 8 d-groups per wave.
  const f16* pa = XhTf + ((size_t)(w * 8) * 256 + (z * jrange >> 5)) * 512 + lane * 8;
  // B: S^T frags for q-groups 2*qt32 (+1), jt from this z's slice.
  const float* pb0 = ST + ((size_t)(qt32 * 2) * 512 + (z * jrange >> 4)) * 256 + lane * 4;
  const float* pb1 = pb0 + (size_t)512 * 256;

  f32x4 acc[8][2] = {};
  float lsum0 = 0.f, lsum1 = 0.f;
  const int nsteps = jrange / 32;

#define LDB(P, I) (*(const f32x4*)((P) + (size_t)(I) * 256))
#define LDA(M, S) (*(const f16x8*)(pa + ((size_t)(M) * 256 + (S)) * 512))

  f32x4 sa0 = LDB(pb0, 0), sa1 = LDB(pb0, 1);
  f32x4 sb0 = LDB(pb1, 0), sb1 = LDB(pb1, 1);
  f32x4 ta0, ta1, tb0, tb1;
  f16x8 a0[8], a1[8];
#pragma unroll
  for (int m2 = 0; m2 < 8; ++m2) a0[m2] = LDA(m2, 0);

#define PV_STEP(SA0, SA1, SB0, SB1, TA0, TA1, TB0, TB1, AC, AN, S)            \
  {                                                                           \
    const int sn_ = ((S) + 1 < nsteps) ? (S) + 1 : (S);                       \
    TA0 = LDB(pb0, 2 * sn_);     TA1 = LDB(pb0, 2 * sn_ + 1);                 \
    TB0 = LDB(pb1, 2 * sn_);     TB1 = LDB(pb1, 2 * sn_ + 1);                 \
    f16x8 b0, b1;                                                             \
    _Pragma("unroll")                                                         \
    for (int i = 0; i < 4; ++i) {                                             \
      float p0 = __expf(SA0[i] - mv0); lsum0 += p0; b0[i] = (f16)p0;          \
      float p1 = __expf(SA1[i] - mv0); lsum0 += p1; b0[4 + i] = (f16)p1;      \
      float p2 = __expf(SB0[i] - mv1); lsum1 += p2; b1[i] = (f16)p2;          \
      float p3 = __expf(SB1[i] - mv1); lsum1 += p3; b1[4 + i] = (f16)p3;      \
    }                                                                         \
    _Pragma("unroll")                                                         \
    for (int m2 = 0; m2 < 8; ++m2) {                                          \
      AN[m2] = LDA(m2, sn_);                                                  \
      acc[m2][0] = __builtin_amdgcn_mfma_f32_16x16x32_f16(AC[m2], b0, acc[m2][0], 0, 0, 0); \
      acc[m2][1] = __builtin_amdgcn_mfma_f32_16x16x32_f16(AC[m2], b1, acc[m2][1], 0, 0, 0); \
    }                                                                         \
  }

  for (int s = 0; s < nsteps; s += 2) {
    PV_STEP(sa0, sa1, sb0, sb1, ta0, ta1, tb0, tb1, a0, a1, s);
    PV_STEP(ta0, ta1, tb0, tb1, sa0, sa1, sb0, sb1, a1, a0, s + 1);
  }
#undef PV_STEP
#undef LDA
#undef LDB

  // l reduce: lanes sharing (lane&15) combine; wave 0 stores.
  lsum0 += __shfl_xor(lsum0, 16);
  lsum0 += __shfl_xor(lsum0, 32);
  lsum1 += __shfl_xor(lsum1, 16);
  lsum1 += __shfl_xor(lsum1, 32);
  if (w == 0 && lane < 16) {
    lpart[(size_t)z * NSEQ + qg0 + lane]      = lsum0;
    lpart[(size_t)z * NSEQ + qg0 + 16 + lane] = lsum1;
  }

  // C: row = d = w*128 + m2*16 + (lane>>4)*4 + r ; col = q = qg0 + n2*16 + (lane&15)
#pragma unroll
  for (int n2 = 0; n2 < 2; ++n2) {
    const int qg = qg0 + n2 * 16 + (lane & 15);
    float* op = obase + (size_t)z * zstride + (size_t)qg * DIM;
#pragma unroll
    for (int m2 = 0; m2 < 8; ++m2)
      *(f32x4*)(op + w * 128 + m2 * 16 + (lane >> 4) * 4) = acc[m2][n2];
  }
}

// ---------------------------------------------------------------------------
// Out[q][d] = (sum_z Opart[z][q][d]) / (sum_z lpart[z][q]).
// Works in place when obase==Out (Z==1, zstride==0).
// ---------------------------------------------------------------------------
__global__ __launch_bounds__(256) void k_reduce2(
    const float* __restrict__ obase, size_t zstride, int Z,
    const float* __restrict__ lpart, float* __restrict__ Out)
{
  const int idx = blockIdx.x * 256 + threadIdx.x;
  const int q = idx >> 7;
  const int d4 = idx & 127;
  const float* p = obase + (size_t)q * DIM + (size_t)d4 * 4;
  f32x4 s = *(const f32x4*)p;
  float l = lpart[q];
  for (int zz = 1; zz < Z; ++zz) {
    s += *(const f32x4*)(p + (size_t)zz * zstride);
    l += lpart[(size_t)zz * NSEQ + q];
  }
  s *= (1.0f / l);
  *(f32x4*)(Out + (size_t)q * DIM + d4 * 4) = s;
}

// ---------------------------------------------------------------------------
extern "C" void kernel_launch(void* const* d_in, const int* in_sizes, int n_in,
                              void* d_out, int out_size, void* d_ws, size_t ws_size,
                              hipStream_t stream) {
  const float* Wq = (const float*)d_in[0];
  const float* Wk = (const float*)d_in[1];
  const float* X  = (const float*)d_in[2];
  float* Out = (float*)d_out;

  char* w = (char*)d_ws;
  const size_t SPLIT = (size_t)NSEQ * DIM * 2;           // 8 MB
  const size_t XFB   = (size_t)NSEQ * DIM * 2;           // 8 MB frag XhTf
  const size_t WTB   = (size_t)DIM * DIM * 2;            // 512 KB
  f16* Qh   = (f16*)(w);
  f16* Ql   = (f16*)(w + SPLIT);
  f16* Kh   = (f16*)(w + 2 * SPLIT);
  f16* Kl   = (f16*)(w + 3 * SPLIT);
  f16* XhTf = (f16*)(w + 4 * SPLIT);
  f16* Xh   = (f16*)(w + 4 * SPLIT + XFB);
  f16* Xl   = (f16*)(w + 5 * SPLIT + XFB);
  f16* Wth  = (f16*)(w + 6 * SPLIT + XFB);
  f16* Wtl  = (f16*)(w + 6 * SPLIT + XFB + WTB);
  float* mrow  = (float*)(w + 6 * SPLIT + XFB + 2 * WTB);              // 32 KB
  float* lpart = (float*)(w + 6 * SPLIT + XFB + 2 * WTB + 32768);      // 128 KB
  const size_t used_base = 6 * SPLIT + XFB + 2 * WTB + 163840;
  char* rest = w + used_base;
  const size_t OPART1 = (size_t)NSEQ * DIM * 4;          // 16 MB per partial
  const size_t avail = (ws_size > used_base) ? ws_size - used_base : 0;

  // pick (CQ, Z): ST chunk = CQ*32KB; partials = Z*16MB (Z>1).
  int CQ = 4096, Z = 4;
  auto need = [&](int cq, int zz) -> size_t {
    return (size_t)cq * NSEQ * 4 + (zz > 1 ? (size_t)zz * OPART1 : 0);
  };
  if (need(CQ, Z) > avail) { CQ = 2048; }
  if (need(CQ, Z) > avail) { Z = 2; }
  if (need(CQ, Z) > avail) { CQ = 1024; }
  if (need(CQ, Z) > avail) { Z = 1; }
  if (need(CQ, Z) > avail) { CQ = 512; }
  if (need(CQ, Z) > avail) { CQ = 256; }

  float* ST = (float*)rest;
  float* obase; size_t zstride;
  if (Z > 1) { obase = (float*)(rest + (size_t)CQ * NSEQ * 4); zstride = (size_t)NSEQ * DIM; }
  else       { obase = Out; zstride = 0; }

  const float SCALE = 0.044194173824159216f;  // 1/sqrt(512)
  k_splitx<<<NSEQ * DIM / (256 * 4), 256, 0, stream>>>(X, Xh, Xl);
  k_xt2<<<dim3(NSEQ / 64, DIM / 64), 256, 0, stream>>>(X, XhTf);
  k_splitwt<<<dim3(8, 8), 256, 0, stream>>>(Wq, Wth, Wtl);
  k_proj<<<dim3(NSEQ / 128, DIM / 128), 256, 0, stream>>>(Xh, Xl, Wth, Wtl, Qh, Ql, SCALE);
  k_splitwt<<<dim3(8, 8), 256, 0, stream>>>(Wk, Wth, Wtl);
  k_proj<<<dim3(NSEQ / 128, DIM / 128), 256, 0, stream>>>(Xh, Xl, Wth, Wtl, Kh, Kl, 1.0f);

  for (int q0 = 0; q0 < NSEQ; q0 += CQ) {
    k_qkt_t<<<dim3(NSEQ / 128, CQ / 128), 256, 0, stream>>>(Kh, Kl, Qh, Ql, ST, q0);
    k_smax<<<dim3(CQ / 16), 256, 0, stream>>>(ST, mrow, q0);
    k_pvx2<<<dim3((CQ / 32) * Z), 256, 0, stream>>>(XhTf, ST, mrow, obase, zstride,
                                                    lpart, q0, NSEQ / Z, Z);
  }
  k_reduce2<<<NSEQ * (DIM / 4) / 256, 256, 0, stream>>>(obase, zstride, Z, lpart, Out);
}